// Round 18
// baseline (144.543 us; speedup 1.0000x reference)
//
#include <hip/hip_runtime.h>
#include <hip/hip_bf16.h>
#include <math.h>

#define BATCH 2
#define SEQ 2048
#define DMODEL 1024
#define NHEAD 16
#define DHEAD 64
#define MTOT (BATCH*SEQ)   // 4096

typedef __attribute__((ext_vector_type(8))) short bf16x8;
typedef __attribute__((ext_vector_type(4))) short short4v;
typedef __attribute__((ext_vector_type(4))) float f32x4;

static __device__ inline short f2bs(float x) {
    __hip_bfloat16 b = __float2bfloat16(x);
    return *reinterpret_cast<short*>(&b);
}

// Async global -> LDS, 16B per lane. LDS dest wave-uniform base.
static __device__ __forceinline__ void gload16(const void* g, void* l) {
    __builtin_amdgcn_global_load_lds(
        (const __attribute__((address_space(1))) unsigned int*)g,
        (__attribute__((address_space(3))) unsigned int*)l,
        16, 0, 0);
}

// ------------------------------------------------------------------
// fp32 -> bf16 conversion, weights only (4 x 1M elems).
// ------------------------------------------------------------------
struct ConvArgs {
    const float* src[4];
    unsigned short* dst[4];
};

__global__ __launch_bounds__(256)
void convert_bf16_kernel(ConvArgs a)
{
    const int r = blockIdx.x >> 9;          // 512 blocks per tensor
    const int b = blockIdx.x & 511;
    const float* s = a.src[r];
    unsigned short* d = a.dst[r];
    const int base = b * 2048 + threadIdx.x * 8;
    const float4 f0 = *reinterpret_cast<const float4*>(&s[base]);
    const float4 f1 = *reinterpret_cast<const float4*>(&s[base + 4]);
    bf16x8 o;
    o[0] = f2bs(f0.x); o[1] = f2bs(f0.y); o[2] = f2bs(f0.z); o[3] = f2bs(f0.w);
    o[4] = f2bs(f1.x); o[5] = f2bs(f1.y); o[6] = f2bs(f1.z); o[7] = f2bs(f1.w);
    *reinterpret_cast<bf16x8*>(&d[base]) = o;
}

// ------------------------------------------------------------------
// MFMA bf16 GEMM core: out = X @ W^T + bias.
// 128x128 tile, BK=64, SINGLE-buffered LDS, reg-prefetch overlapping
// the MFMA cluster, 2 barriers per K-step.
// XF32=1: X is fp32, converted to bf16 during staging — valid ONLY
// with the XCD-chunked grid swizzle (X-panel re-reads become L2 hits).
// ------------------------------------------------------------------
template<int SPLIT, int XF32>
static __device__ __forceinline__
void gemm_core(const void* __restrict__ Xp, const short* __restrict__ Wg,
               const float* __restrict__ bias, void* __restrict__ outp,
               float scale, int m0, int n0)
{
    __shared__ short Xs[128 * 64];
    __shared__ short Wt[128 * 64];

    const int t    = threadIdx.x;
    const int lane = t & 63;
    const int w    = t >> 6;
    const int wm   = w >> 1, wn = w & 1;
    const int m_   = lane & 15, g = lane >> 4;

    const int sr  = t >> 1;
    const int sc0 = (t & 1) * 4;

    f32x4 acc[4][4] = {};
    bf16x8 xr[4], wr[4];

    auto ldx = [&](size_t idx) -> bf16x8 {
        if (XF32) {
            const float* p = (const float*)Xp + idx;
            const float4 f0 = *reinterpret_cast<const float4*>(p);
            const float4 f1 = *reinterpret_cast<const float4*>(p + 4);
            bf16x8 o;
            o[0] = f2bs(f0.x); o[1] = f2bs(f0.y); o[2] = f2bs(f0.z); o[3] = f2bs(f0.w);
            o[4] = f2bs(f1.x); o[5] = f2bs(f1.y); o[6] = f2bs(f1.z); o[7] = f2bs(f1.w);
            return o;
        } else {
            return *reinterpret_cast<const bf16x8*>((const short*)Xp + idx);
        }
    };

    auto ldtile = [&](int k0) {
        #pragma unroll
        for (int c = 0; c < 4; ++c) {
            xr[c] = ldx((size_t)(m0 + sr) * DMODEL + k0 + (sc0 + c) * 8);
            wr[c] = *reinterpret_cast<const bf16x8*>(&Wg[(size_t)(n0 + sr) * DMODEL + k0 + (sc0 + c) * 8]);
        }
    };
    auto sttile = [&]() {
        #pragma unroll
        for (int c = 0; c < 4; ++c) {
            const int byo = sr * 128 + (((sc0 + c) * 16) ^ ((sr & 7) << 4));
            *reinterpret_cast<bf16x8*>((char*)Xs + byo) = xr[c];
            *reinterpret_cast<bf16x8*>((char*)Wt + byo) = wr[c];
        }
    };

    ldtile(0);
    sttile();
    __syncthreads();

    for (int kt = 0; kt < DMODEL / 64; ++kt) {
        const bool more = (kt < DMODEL / 64 - 1);
        if (more) ldtile((kt + 1) * 64);   // global loads fly during MFMA phase

        bf16x8 af[4][2], bfr[4][2];
        #pragma unroll
        for (int mt = 0; mt < 4; ++mt) {
            const int row = wm * 64 + mt * 16 + m_;
            #pragma unroll
            for (int kc = 0; kc < 2; ++kc)
                af[mt][kc] = *reinterpret_cast<const bf16x8*>(
                    (char*)Xs + row * 128 + ((kc * 64 + g * 16) ^ ((row & 7) << 4)));
        }
        #pragma unroll
        for (int nt = 0; nt < 4; ++nt) {
            const int row = wn * 64 + nt * 16 + m_;
            #pragma unroll
            for (int kc = 0; kc < 2; ++kc)
                bfr[nt][kc] = *reinterpret_cast<const bf16x8*>(
                    (char*)Wt + row * 128 + ((kc * 64 + g * 16) ^ ((row & 7) << 4)));
        }

        __builtin_amdgcn_s_setprio(1);
        #pragma unroll
        for (int mt = 0; mt < 4; ++mt)
            #pragma unroll
            for (int nt = 0; nt < 4; ++nt)
                #pragma unroll
                for (int kc = 0; kc < 2; ++kc)
                    acc[mt][nt] = __builtin_amdgcn_mfma_f32_16x16x32_bf16(
                        af[mt][kc], bfr[nt][kc], acc[mt][nt], 0, 0, 0);
        __builtin_amdgcn_s_setprio(0);

        __syncthreads();                   // all waves done reading this tile
        if (more) sttile();                // overwrite with prefetched tile
        __syncthreads();                   // writes visible
    }

    float bv[4];
    #pragma unroll
    for (int nt = 0; nt < 4; ++nt) bv[nt] = bias[n0 + wn * 64 + nt * 16 + m_];

    #pragma unroll
    for (int mt = 0; mt < 4; ++mt) {
        #pragma unroll
        for (int r = 0; r < 4; ++r) {
            const int row = m0 + wm * 64 + mt * 16 + g * 4 + r;
            const int b = row >> 11;
            const int s = row & 2047;
            #pragma unroll
            for (int nt = 0; nt < 4; ++nt) {
                const int n = n0 + wn * 64 + nt * 16 + m_;
                const float c = (acc[mt][nt][r] + bv[nt]) * scale;
                if (SPLIT) {
                    const int h = n >> 6, dk = n & 63;
                    ((__hip_bfloat16*)outp)[(((size_t)(b * NHEAD + h)) * SEQ + s) * DHEAD + dk]
                        = __float2bfloat16(c);
                } else {
                    ((float*)outp)[(size_t)row * DMODEL + n] = c;
                }
            }
        }
    }
}

// Fused Q/K/V projection: grid 768 = 8 XCD-chunks x 96 contiguous tiles.
// X inputs are the ORIGINAL fp32 tensors (converted during staging).
struct TrioArgs {
    const float* X[3];
    const short* W[3];
    const float* bias[3];
    __hip_bfloat16* out[3];
    float scale[3];
};

__global__ __launch_bounds__(256)
void gemm_qkv_kernel(TrioArgs a)
{
    const int bid = blockIdx.x;
    const int swz = (bid & 7) * 96 + (bid >> 3);
    const int which = swz >> 8;              // 0..2
    const int tile  = swz & 255;             // 0..255
    const int n0 = (tile & 7) * 128;
    const int m0 = (tile >> 3) * 128;
    gemm_core<1, 1>(a.X[which], a.W[which], a.bias[which], a.out[which],
                    a.scale[which], m0, n0);
}

__global__ __launch_bounds__(256)
void gemm_out_kernel(const short* __restrict__ X, const short* __restrict__ W,
                     const float* __restrict__ bias, float* __restrict__ out)
{
    const int bid = blockIdx.x;
    const int swz = (bid & 7) * 32 + (bid >> 3);   // 256 = 8 x 32
    const int n0 = (swz & 7) * 128;
    const int m0 = (swz >> 3) * 128;
    gemm_core<0, 0>(X, W, bias, out, 1.0f, m0, n0);
}

// ------------------------------------------------------------------
// Paired-tile MFMA causal flash attention, 8 waves / 512 threads.
// Swapped operands; producer/consumer split (waves 0-3 stage);
// exp2-domain softmax with defer-max. (Round-11/14/17 validated.)
// ------------------------------------------------------------------
__global__ __launch_bounds__(512, 4)
void attn_mfma_kernel(const __hip_bfloat16* __restrict__ Q,
                      const __hip_bfloat16* __restrict__ K,
                      const __hip_bfloat16* __restrict__ V,
                      __hip_bfloat16* __restrict__ ctx)
{
    __shared__ short Ks[2][64 * 64];    // K tile [kv][d], swizzled rows
    __shared__ short Vts[2][64 * 64];   // V^T tile [d][kv], swizzled rows
    __shared__ short Ps[8 * 16 * 72];   // per-wave P [q][k], stride 72

    const int t    = threadIdx.x;
    const int lane = t & 63;
    const int w    = t >> 6;        // 0..7
    const int wq   = w & 3;         // wave-within-side
    const int side = w >> 2;        // 0 = tile A (stager), 1 = tile B
    const int m    = lane & 15;
    const int g    = lane >> 4;

    // XCD-chunked swizzle: 512 blocks = 8 XCDs x 64
    const int bid = blockIdx.x;
    const int swz = (bid & 7) * 64 + (bid >> 3);
    const int bh  = swz >> 4;       // 0..31
    const int pr  = swz & 15;       // 0..15
    const int qtA = pr, qtB = 31 - pr;
    const int myqt = side ? qtB : qtA;
    const int q0   = myqt * 64;

    const __hip_bfloat16* Qb = Q + (size_t)bh * SEQ * DHEAD;
    const __hip_bfloat16* Kb = K + (size_t)bh * SEQ * DHEAD;
    const __hip_bfloat16* Vb = V + (size_t)bh * SEQ * DHEAD;

    // staging geometry (only threads t<256 use these)
    const int sKrb = 16 * (w & 3);          // K row base for stager wave
    const int krl  = lane >> 3;             // row within 8-row chunk
    const int kcs  = (lane & 7) ^ krl;      // pre-swizzled source chunk
    const int vk   = t & 63;                // V kv row
    const int vd0  = ((t >> 6) & 3) * 16;   // V d segment base

    bf16x8 vreg0, vreg1;
    auto stageK = [&](int k0s, int buf) {
        #pragma unroll
        for (int c2 = 0; c2 < 2; ++c2) {
            const int rb = sKrb + 8 * c2;
            gload16(Kb + (size_t)(k0s + rb + krl) * DHEAD + kcs * 8,
                    &Ks[buf][rb * 64]);
        }
    };
    auto loadV = [&](int k0s) {
        vreg0 = *reinterpret_cast<const bf16x8*>(&Vb[(size_t)(k0s + vk) * DHEAD + vd0]);
        vreg1 = *reinterpret_cast<const bf16x8*>(&Vb[(size_t)(k0s + vk) * DHEAD + vd0 + 8]);
    };
    auto writeV = [&](int buf) {
        #pragma unroll
        for (int j = 0; j < 8; ++j) {
            const int d = vd0 + j;
            *reinterpret_cast<short*>((char*)Vts[buf] +
                (((d * 128) + vk * 2) ^ ((d & 7) << 4))) = vreg0[j];
        }
        #pragma unroll
        for (int j = 0; j < 8; ++j) {
            const int d = vd0 + 8 + j;
            *reinterpret_cast<short*>((char*)Vts[buf] +
                (((d * 128) + vk * 2) ^ ((d & 7) << 4))) = vreg1[j];
        }
    };

    // Q fragments (B-operand of S^T); Q pre-scaled by 0.125*log2e
    bf16x8 qf[2];
    #pragma unroll
    for (int c = 0; c < 2; ++c)
        qf[c] = *reinterpret_cast<const bf16x8*>(
            &Qb[(size_t)(q0 + 16 * wq + m) * DHEAD + c * 32 + 8 * g]);

    f32x4 o[4] = {};       // O^T: o[dt][r] = O[q=m][d=dt*16+4g+r]
    float mr = -INFINITY, lr = 0.0f;

    short* Pw = Ps + w * 16 * 72;

    // prologue: side A stages kv-tile 0
    if (t < 256) { stageK(0, 0); loadV(0); writeV(0); }
    __syncthreads();

    int cur = 0;
    for (int kt = 0; kt <= qtB; ++kt) {
        const bool more = (kt < qtB);
        if (t < 256 && more) {           // async prefetch of tile kt+1
            stageK((kt + 1) * 64, cur ^ 1);
            loadV((kt + 1) * 64);
        }

        if (kt <= myqt) {
            // ---- S^T = K Q^T (log2 domain) ----
            f32x4 s[4] = {};
            __builtin_amdgcn_s_setprio(1);
            #pragma unroll
            for (int ct = 0; ct < 4; ++ct) {
                const int krow = ct * 16 + m;
                #pragma unroll
                for (int c = 0; c < 2; ++c) {
                    const bf16x8 kf = *reinterpret_cast<const bf16x8*>((char*)Ks[cur] +
                        (((krow * 128) + c * 64 + 16 * g) ^ ((krow & 7) << 4)));
                    s[ct] = __builtin_amdgcn_mfma_f32_16x16x32_bf16(kf, qf[c], s[ct], 0, 0, 0);
                }
            }
            __builtin_amdgcn_s_setprio(0);

            // ---- causal mask on diagonal tile ----
            if (kt == myqt) {
                const int qr = 16 * wq + m;
                #pragma unroll
                for (int ct = 0; ct < 4; ++ct)
                    #pragma unroll
                    for (int r = 0; r < 4; ++r)
                        if (ct * 16 + 4 * g + r > qr) s[ct][r] = -INFINITY;
            }

            // ---- tile max + 2 shfl ----
            float pmax = fmaxf(fmaxf(s[0][0], s[0][1]), fmaxf(s[0][2], s[0][3]));
            pmax = fmaxf(fmaxf(pmax, s[1][0]), s[1][1]);
            pmax = fmaxf(fmaxf(pmax, s[1][2]), s[1][3]);
            pmax = fmaxf(fmaxf(pmax, s[2][0]), s[2][1]);
            pmax = fmaxf(fmaxf(pmax, s[2][2]), s[2][3]);
            pmax = fmaxf(fmaxf(pmax, s[3][0]), s[3][1]);
            pmax = fmaxf(fmaxf(pmax, s[3][2]), s[3][3]);
            pmax = fmaxf(pmax, __shfl_xor(pmax, 16, 64));
            pmax = fmaxf(pmax, __shfl_xor(pmax, 32, 64));

            // ---- defer-max (THR=8 in log2 units) ----
            if (!__all(pmax <= mr + 8.0f)) {
                const float mnew = fmaxf(mr, pmax);
                const float scl  = __builtin_amdgcn_exp2f(mr - mnew); // -inf -> 0
                mr = mnew;
                lr *= scl;
                #pragma unroll
                for (int dt = 0; dt < 4; ++dt)
                    #pragma unroll
                    for (int r = 0; r < 4; ++r)
                        o[dt][r] *= scl;
            }

            // ---- P = exp2(S - m); row-sum ----
            float psum = 0.0f;
            #pragma unroll
            for (int ct = 0; ct < 4; ++ct) {
                #pragma unroll
                for (int r = 0; r < 4; ++r) {
                    s[ct][r] = __builtin_amdgcn_exp2f(s[ct][r] - mr);
                    psum += s[ct][r];
                }
            }
            psum += __shfl_xor(psum, 16, 64);
            psum += __shfl_xor(psum, 32, 64);
            lr += psum;

            // ---- P -> bf16 LDS (per-wave region) ----
            #pragma unroll
            for (int ct = 0; ct < 4; ++ct) {
                short4v p4;
                p4[0] = f2bs(s[ct][0]); p4[1] = f2bs(s[ct][1]);
                p4[2] = f2bs(s[ct][2]); p4[3] = f2bs(s[ct][3]);
                *reinterpret_cast<short4v*>(&Pw[m * 72 + ct * 16 + 4 * g]) = p4;
            }

            bf16x8 pf[2];
            #pragma unroll
            for (int c = 0; c < 2; ++c)
                pf[c] = *reinterpret_cast<const bf16x8*>(&Pw[m * 72 + c * 32 + 8 * g]);

            // ---- O^T += V^T P^T ----
            __builtin_amdgcn_s_setprio(1);
            #pragma unroll
            for (int dt = 0; dt < 4; ++dt) {
                const int vrow = dt * 16 + m;
                #pragma unroll
                for (int c = 0; c < 2; ++c) {
                    const bf16x8 vf = *reinterpret_cast<const bf16x8*>((char*)Vts[cur] +
                        (((vrow * 128) + c * 64 + 16 * g) ^ ((vrow & 7) << 4)));
                    o[dt] = __builtin_amdgcn_mfma_f32_16x16x32_bf16(vf, pf[c], o[dt], 0, 0, 0);
                }
            }
            __builtin_amdgcn_s_setprio(0);
        }

        if (t < 256 && more) writeV(cur ^ 1);   // V^T lands late (T14)
        __syncthreads();                        // single barrier per kv-tile
        cur ^= 1;
    }

    // ---- epilogue: lane owns q-row m; 8B packed stores ----
    const int b = bh >> 4;
    const int h = bh & 15;
    const float inv = 1.0f / lr;
    const int row = q0 + 16 * wq + m;
    short* dst = (short*)&ctx[((size_t)(b * SEQ) + row) * DMODEL + h * DHEAD];
    #pragma unroll
    for (int dt = 0; dt < 4; ++dt) {
        short4v p4;
        p4[0] = f2bs(o[dt][0] * inv); p4[1] = f2bs(o[dt][1] * inv);
        p4[2] = f2bs(o[dt][2] * inv); p4[3] = f2bs(o[dt][3] * inv);
        *reinterpret_cast<short4v*>(dst + dt * 16 + 4 * g) = p4;
    }
}

// ------------------------------------------------------------------
extern "C" void kernel_launch(void* const* d_in, const int* in_sizes, int n_in,
                              void* d_out, int out_size, void* d_ws, size_t ws_size,
                              hipStream_t stream)
{
    const float* query = (const float*)d_in[0];
    const float* key   = (const float*)d_in[1];
    const float* value = (const float*)d_in[2];
    // d_in[3] = mask: fixed causal tril — implemented directly
    const float* Wq = (const float*)d_in[4];
    const float* bq = (const float*)d_in[5];
    const float* Wk = (const float*)d_in[6];
    const float* bk = (const float*)d_in[7];
    const float* Wv = (const float*)d_in[8];
    const float* bv = (const float*)d_in[9];
    const float* Wo = (const float*)d_in[10];
    const float* bo = (const float*)d_in[11];
    float* out = (float*)d_out;

    // ws layout: wqb/wkb/wvb/wob bf16 (2MB each) at 0..8MB;
    //            qb 8..16MB, kb 16..24MB, vb 24..32MB ([B,H,S,DK] bf16);
    //            ctx 32..40MB ([B,S,D] bf16)
    char* ws = (char*)d_ws;
    const size_t MB = 1024 * 1024;
    unsigned short* wqb = (unsigned short*)(ws + 0 * MB);
    unsigned short* wkb = (unsigned short*)(ws + 2 * MB);
    unsigned short* wvb = (unsigned short*)(ws + 4 * MB);
    unsigned short* wob = (unsigned short*)(ws + 6 * MB);
    __hip_bfloat16* qb  = (__hip_bfloat16*)(ws + 8 * MB);
    __hip_bfloat16* kb  = (__hip_bfloat16*)(ws + 16 * MB);
    __hip_bfloat16* vb  = (__hip_bfloat16*)(ws + 24 * MB);
    __hip_bfloat16* ctx = (__hip_bfloat16*)(ws + 32 * MB);

    ConvArgs ca;
    ca.src[0] = Wq; ca.dst[0] = wqb;
    ca.src[1] = Wk; ca.dst[1] = wkb;
    ca.src[2] = Wv; ca.dst[2] = wvb;
    ca.src[3] = Wo; ca.dst[3] = wob;
    convert_bf16_kernel<<<dim3(2048), dim3(256), 0, stream>>>(ca);

    TrioArgs ta;
    // Q scale folds 1/sqrt(64) AND log2(e) for the exp2-domain softmax.
    ta.X[0] = query; ta.W[0] = (const short*)wqb; ta.bias[0] = bq;
    ta.out[0] = qb; ta.scale[0] = 0.125f * 1.44269504f;
    ta.X[1] = key;   ta.W[1] = (const short*)wkb; ta.bias[1] = bk;
    ta.out[1] = kb; ta.scale[1] = 1.0f;
    ta.X[2] = value; ta.W[2] = (const short*)wvb; ta.bias[2] = bv;
    ta.out[2] = vb; ta.scale[2] = 1.0f;
    gemm_qkv_kernel<<<dim3(768), dim3(256), 0, stream>>>(ta);

    attn_mfma_kernel<<<dim3(512), dim3(512), 0, stream>>>(qb, kb, vb, ctx);

    gemm_out_kernel<<<dim3(256), dim3(256), 0, stream>>>(
        (const short*)ctx, (const short*)wob, bo, out);
}

// Round 19
// 116.345 us; speedup vs baseline: 1.2424x; 1.2424x over previous
//
#include <hip/hip_runtime.h>
#include <hip/hip_bf16.h>
#include <math.h>

#define BATCH 2
#define SEQ 2048
#define DMODEL 1024
#define NHEAD 16
#define DHEAD 64
#define MTOT (BATCH*SEQ)   // 4096

typedef __attribute__((ext_vector_type(8))) short bf16x8;
typedef __attribute__((ext_vector_type(4))) short short4v;
typedef __attribute__((ext_vector_type(4))) float f32x4;

static __device__ inline short f2bs(float x) {
    __hip_bfloat16 b = __float2bfloat16(x);
    return *reinterpret_cast<short*>(&b);
}

// Async global -> LDS, 16B per lane. LDS dest wave-uniform base.
static __device__ __forceinline__ void gload16(const void* g, void* l) {
    __builtin_amdgcn_global_load_lds(
        (const __attribute__((address_space(1))) unsigned int*)g,
        (__attribute__((address_space(3))) unsigned int*)l,
        16, 0, 0);
}

// ------------------------------------------------------------------
// Batched fp32 -> bf16 conversion over 7 tensors (3 inputs, 4 weights).
// ------------------------------------------------------------------
struct ConvArgs {
    const float* src[7];
    unsigned short* dst[7];
    int nblk[7];
};

__global__ __launch_bounds__(256)
void convert_bf16_kernel(ConvArgs a)
{
    int b = blockIdx.x;
    int r = 0;
    while (b >= a.nblk[r]) { b -= a.nblk[r]; ++r; }
    const float* s = a.src[r];
    unsigned short* d = a.dst[r];
    const int base = b * 2048 + threadIdx.x * 8;
    const float4 f0 = *reinterpret_cast<const float4*>(&s[base]);
    const float4 f1 = *reinterpret_cast<const float4*>(&s[base + 4]);
    bf16x8 o;
    o[0] = f2bs(f0.x); o[1] = f2bs(f0.y); o[2] = f2bs(f0.z); o[3] = f2bs(f0.w);
    o[4] = f2bs(f1.x); o[5] = f2bs(f1.y); o[6] = f2bs(f1.z); o[7] = f2bs(f1.w);
    *reinterpret_cast<bf16x8*>(&d[base]) = o;
}

// ------------------------------------------------------------------
// MFMA bf16 GEMM core: out = X @ W^T + bias.
// 128x128 tile, BK=64, SINGLE-buffered LDS (32KB -> high blocks/CU),
// reg-prefetch overlapping the MFMA cluster, 2 barriers per K-step.
// (Validated best across r8/r15/r18 A/Bs: gload_lds and XF32-staging
// variants both regress — staging latency on the 2-barrier critical
// path; reg-staging only waits on fast ds_writes.)
// ------------------------------------------------------------------
template<int SPLIT>
static __device__ __forceinline__
void gemm_core(const short* __restrict__ Xg, const short* __restrict__ Wg,
               const float* __restrict__ bias, void* __restrict__ outp,
               float scale, int m0, int n0)
{
    __shared__ short Xs[128 * 64];
    __shared__ short Wt[128 * 64];

    const int t    = threadIdx.x;
    const int lane = t & 63;
    const int w    = t >> 6;
    const int wm   = w >> 1, wn = w & 1;
    const int m_   = lane & 15, g = lane >> 4;

    const int sr  = t >> 1;
    const int sc0 = (t & 1) * 4;

    f32x4 acc[4][4] = {};
    bf16x8 xr[4], wr[4];

    auto ldtile = [&](int k0) {
        #pragma unroll
        for (int c = 0; c < 4; ++c) {
            xr[c] = *reinterpret_cast<const bf16x8*>(&Xg[(size_t)(m0 + sr) * DMODEL + k0 + (sc0 + c) * 8]);
            wr[c] = *reinterpret_cast<const bf16x8*>(&Wg[(size_t)(n0 + sr) * DMODEL + k0 + (sc0 + c) * 8]);
        }
    };
    auto sttile = [&]() {
        #pragma unroll
        for (int c = 0; c < 4; ++c) {
            const int byo = sr * 128 + (((sc0 + c) * 16) ^ ((sr & 7) << 4));
            *reinterpret_cast<bf16x8*>((char*)Xs + byo) = xr[c];
            *reinterpret_cast<bf16x8*>((char*)Wt + byo) = wr[c];
        }
    };

    ldtile(0);
    sttile();
    __syncthreads();

    for (int kt = 0; kt < DMODEL / 64; ++kt) {
        const bool more = (kt < DMODEL / 64 - 1);
        if (more) ldtile((kt + 1) * 64);   // global loads fly during MFMA phase

        bf16x8 af[4][2], bfr[4][2];
        #pragma unroll
        for (int mt = 0; mt < 4; ++mt) {
            const int row = wm * 64 + mt * 16 + m_;
            #pragma unroll
            for (int kc = 0; kc < 2; ++kc)
                af[mt][kc] = *reinterpret_cast<const bf16x8*>(
                    (char*)Xs + row * 128 + ((kc * 64 + g * 16) ^ ((row & 7) << 4)));
        }
        #pragma unroll
        for (int nt = 0; nt < 4; ++nt) {
            const int row = wn * 64 + nt * 16 + m_;
            #pragma unroll
            for (int kc = 0; kc < 2; ++kc)
                bfr[nt][kc] = *reinterpret_cast<const bf16x8*>(
                    (char*)Wt + row * 128 + ((kc * 64 + g * 16) ^ ((row & 7) << 4)));
        }

        __builtin_amdgcn_s_setprio(1);
        #pragma unroll
        for (int mt = 0; mt < 4; ++mt)
            #pragma unroll
            for (int nt = 0; nt < 4; ++nt)
                #pragma unroll
                for (int kc = 0; kc < 2; ++kc)
                    acc[mt][nt] = __builtin_amdgcn_mfma_f32_16x16x32_bf16(
                        af[mt][kc], bfr[nt][kc], acc[mt][nt], 0, 0, 0);
        __builtin_amdgcn_s_setprio(0);

        __syncthreads();                   // all waves done reading this tile
        if (more) sttile();                // overwrite with prefetched tile
        __syncthreads();                   // writes visible
    }

    float bv[4];
    #pragma unroll
    for (int nt = 0; nt < 4; ++nt) bv[nt] = bias[n0 + wn * 64 + nt * 16 + m_];

    #pragma unroll
    for (int mt = 0; mt < 4; ++mt) {
        #pragma unroll
        for (int r = 0; r < 4; ++r) {
            const int row = m0 + wm * 64 + mt * 16 + g * 4 + r;
            const int b = row >> 11;
            const int s = row & 2047;
            #pragma unroll
            for (int nt = 0; nt < 4; ++nt) {
                const int n = n0 + wn * 64 + nt * 16 + m_;
                const float c = (acc[mt][nt][r] + bv[nt]) * scale;
                if (SPLIT) {
                    const int h = n >> 6, dk = n & 63;
                    ((__hip_bfloat16*)outp)[(((size_t)(b * NHEAD + h)) * SEQ + s) * DHEAD + dk]
                        = __float2bfloat16(c);
                } else {
                    ((float*)outp)[(size_t)row * DMODEL + n] = c;
                }
            }
        }
    }
}

// Fused Q/K/V projection: grid 768 = 8 XCD-chunks x 96 contiguous tiles.
struct TrioArgs {
    const short* X[3];
    const short* W[3];
    const float* bias[3];
    __hip_bfloat16* out[3];
    float scale[3];
};

__global__ __launch_bounds__(256)
void gemm_qkv_kernel(TrioArgs a)
{
    const int bid = blockIdx.x;
    const int swz = (bid & 7) * 96 + (bid >> 3);
    const int which = swz >> 8;              // 0..2
    const int tile  = swz & 255;             // 0..255
    const int n0 = (tile & 7) * 128;
    const int m0 = (tile >> 3) * 128;
    gemm_core<1>(a.X[which], a.W[which], a.bias[which], a.out[which],
                 a.scale[which], m0, n0);
}

__global__ __launch_bounds__(256)
void gemm_out_kernel(const short* __restrict__ X, const short* __restrict__ W,
                     const float* __restrict__ bias, float* __restrict__ out)
{
    const int bid = blockIdx.x;
    const int swz = (bid & 7) * 32 + (bid >> 3);   // 256 = 8 x 32
    const int n0 = (swz & 7) * 128;
    const int m0 = (swz >> 3) * 128;
    gemm_core<0>(X, W, bias, out, 1.0f, m0, n0);
}

// ------------------------------------------------------------------
// Paired-tile MFMA causal flash attention, 8 waves / 512 threads.
// Swapped operands; producer/consumer split (waves 0-3 stage);
// exp2-domain softmax with defer-max. (Round-11/14/17 validated.)
// ------------------------------------------------------------------
__global__ __launch_bounds__(512, 4)
void attn_mfma_kernel(const __hip_bfloat16* __restrict__ Q,
                      const __hip_bfloat16* __restrict__ K,
                      const __hip_bfloat16* __restrict__ V,
                      __hip_bfloat16* __restrict__ ctx)
{
    __shared__ short Ks[2][64 * 64];    // K tile [kv][d], swizzled rows
    __shared__ short Vts[2][64 * 64];   // V^T tile [d][kv], swizzled rows
    __shared__ short Ps[8 * 16 * 72];   // per-wave P [q][k], stride 72

    const int t    = threadIdx.x;
    const int lane = t & 63;
    const int w    = t >> 6;        // 0..7
    const int wq   = w & 3;         // wave-within-side
    const int side = w >> 2;        // 0 = tile A (stager), 1 = tile B
    const int m    = lane & 15;
    const int g    = lane >> 4;

    // XCD-chunked swizzle: 512 blocks = 8 XCDs x 64
    const int bid = blockIdx.x;
    const int swz = (bid & 7) * 64 + (bid >> 3);
    const int bh  = swz >> 4;       // 0..31
    const int pr  = swz & 15;       // 0..15
    const int qtA = pr, qtB = 31 - pr;
    const int myqt = side ? qtB : qtA;
    const int q0   = myqt * 64;

    const __hip_bfloat16* Qb = Q + (size_t)bh * SEQ * DHEAD;
    const __hip_bfloat16* Kb = K + (size_t)bh * SEQ * DHEAD;
    const __hip_bfloat16* Vb = V + (size_t)bh * SEQ * DHEAD;

    // staging geometry (only threads t<256 use these)
    const int sKrb = 16 * (w & 3);          // K row base for stager wave
    const int krl  = lane >> 3;             // row within 8-row chunk
    const int kcs  = (lane & 7) ^ krl;      // pre-swizzled source chunk
    const int vk   = t & 63;                // V kv row
    const int vd0  = ((t >> 6) & 3) * 16;   // V d segment base

    bf16x8 vreg0, vreg1;
    auto stageK = [&](int k0s, int buf) {
        #pragma unroll
        for (int c2 = 0; c2 < 2; ++c2) {
            const int rb = sKrb + 8 * c2;
            gload16(Kb + (size_t)(k0s + rb + krl) * DHEAD + kcs * 8,
                    &Ks[buf][rb * 64]);
        }
    };
    auto loadV = [&](int k0s) {
        vreg0 = *reinterpret_cast<const bf16x8*>(&Vb[(size_t)(k0s + vk) * DHEAD + vd0]);
        vreg1 = *reinterpret_cast<const bf16x8*>(&Vb[(size_t)(k0s + vk) * DHEAD + vd0 + 8]);
    };
    auto writeV = [&](int buf) {
        #pragma unroll
        for (int j = 0; j < 8; ++j) {
            const int d = vd0 + j;
            *reinterpret_cast<short*>((char*)Vts[buf] +
                (((d * 128) + vk * 2) ^ ((d & 7) << 4))) = vreg0[j];
        }
        #pragma unroll
        for (int j = 0; j < 8; ++j) {
            const int d = vd0 + 8 + j;
            *reinterpret_cast<short*>((char*)Vts[buf] +
                (((d * 128) + vk * 2) ^ ((d & 7) << 4))) = vreg1[j];
        }
    };

    // Q fragments (B-operand of S^T); Q pre-scaled by 0.125*log2e
    bf16x8 qf[2];
    #pragma unroll
    for (int c = 0; c < 2; ++c)
        qf[c] = *reinterpret_cast<const bf16x8*>(
            &Qb[(size_t)(q0 + 16 * wq + m) * DHEAD + c * 32 + 8 * g]);

    f32x4 o[4] = {};       // O^T: o[dt][r] = O[q=m][d=dt*16+4g+r]
    float mr = -INFINITY, lr = 0.0f;

    short* Pw = Ps + w * 16 * 72;

    // prologue: side A stages kv-tile 0
    if (t < 256) { stageK(0, 0); loadV(0); writeV(0); }
    __syncthreads();

    int cur = 0;
    for (int kt = 0; kt <= qtB; ++kt) {
        const bool more = (kt < qtB);
        if (t < 256 && more) {           // async prefetch of tile kt+1
            stageK((kt + 1) * 64, cur ^ 1);
            loadV((kt + 1) * 64);
        }

        if (kt <= myqt) {
            // ---- S^T = K Q^T (log2 domain) ----
            f32x4 s[4] = {};
            __builtin_amdgcn_s_setprio(1);
            #pragma unroll
            for (int ct = 0; ct < 4; ++ct) {
                const int krow = ct * 16 + m;
                #pragma unroll
                for (int c = 0; c < 2; ++c) {
                    const bf16x8 kf = *reinterpret_cast<const bf16x8*>((char*)Ks[cur] +
                        (((krow * 128) + c * 64 + 16 * g) ^ ((krow & 7) << 4)));
                    s[ct] = __builtin_amdgcn_mfma_f32_16x16x32_bf16(kf, qf[c], s[ct], 0, 0, 0);
                }
            }
            __builtin_amdgcn_s_setprio(0);

            // ---- causal mask on diagonal tile ----
            if (kt == myqt) {
                const int qr = 16 * wq + m;
                #pragma unroll
                for (int ct = 0; ct < 4; ++ct)
                    #pragma unroll
                    for (int r = 0; r < 4; ++r)
                        if (ct * 16 + 4 * g + r > qr) s[ct][r] = -INFINITY;
            }

            // ---- tile max + 2 shfl ----
            float pmax = fmaxf(fmaxf(s[0][0], s[0][1]), fmaxf(s[0][2], s[0][3]));
            pmax = fmaxf(fmaxf(pmax, s[1][0]), s[1][1]);
            pmax = fmaxf(fmaxf(pmax, s[1][2]), s[1][3]);
            pmax = fmaxf(fmaxf(pmax, s[2][0]), s[2][1]);
            pmax = fmaxf(fmaxf(pmax, s[2][2]), s[2][3]);
            pmax = fmaxf(fmaxf(pmax, s[3][0]), s[3][1]);
            pmax = fmaxf(fmaxf(pmax, s[3][2]), s[3][3]);
            pmax = fmaxf(pmax, __shfl_xor(pmax, 16, 64));
            pmax = fmaxf(pmax, __shfl_xor(pmax, 32, 64));

            // ---- defer-max (THR=8 in log2 units) ----
            if (!__all(pmax <= mr + 8.0f)) {
                const float mnew = fmaxf(mr, pmax);
                const float scl  = __builtin_amdgcn_exp2f(mr - mnew); // -inf -> 0
                mr = mnew;
                lr *= scl;
                #pragma unroll
                for (int dt = 0; dt < 4; ++dt)
                    #pragma unroll
                    for (int r = 0; r < 4; ++r)
                        o[dt][r] *= scl;
            }

            // ---- P = exp2(S - m); row-sum ----
            float psum = 0.0f;
            #pragma unroll
            for (int ct = 0; ct < 4; ++ct) {
                #pragma unroll
                for (int r = 0; r < 4; ++r) {
                    s[ct][r] = __builtin_amdgcn_exp2f(s[ct][r] - mr);
                    psum += s[ct][r];
                }
            }
            psum += __shfl_xor(psum, 16, 64);
            psum += __shfl_xor(psum, 32, 64);
            lr += psum;

            // ---- P -> bf16 LDS (per-wave region) ----
            #pragma unroll
            for (int ct = 0; ct < 4; ++ct) {
                short4v p4;
                p4[0] = f2bs(s[ct][0]); p4[1] = f2bs(s[ct][1]);
                p4[2] = f2bs(s[ct][2]); p4[3] = f2bs(s[ct][3]);
                *reinterpret_cast<short4v*>(&Pw[m * 72 + ct * 16 + 4 * g]) = p4;
            }

            bf16x8 pf[2];
            #pragma unroll
            for (int c = 0; c < 2; ++c)
                pf[c] = *reinterpret_cast<const bf16x8*>(&Pw[m * 72 + c * 32 + 8 * g]);

            // ---- O^T += V^T P^T ----
            __builtin_amdgcn_s_setprio(1);
            #pragma unroll
            for (int dt = 0; dt < 4; ++dt) {
                const int vrow = dt * 16 + m;
                #pragma unroll
                for (int c = 0; c < 2; ++c) {
                    const bf16x8 vf = *reinterpret_cast<const bf16x8*>((char*)Vts[cur] +
                        (((vrow * 128) + c * 64 + 16 * g) ^ ((vrow & 7) << 4)));
                    o[dt] = __builtin_amdgcn_mfma_f32_16x16x32_bf16(vf, pf[c], o[dt], 0, 0, 0);
                }
            }
            __builtin_amdgcn_s_setprio(0);
        }

        if (t < 256 && more) writeV(cur ^ 1);   // V^T lands late (T14)
        __syncthreads();                        // single barrier per kv-tile
        cur ^= 1;
    }

    // ---- epilogue: lane owns q-row m; 8B packed stores ----
    const int b = bh >> 4;
    const int h = bh & 15;
    const float inv = 1.0f / lr;
    const int row = q0 + 16 * wq + m;
    short* dst = (short*)&ctx[((size_t)(b * SEQ) + row) * DMODEL + h * DHEAD];
    #pragma unroll
    for (int dt = 0; dt < 4; ++dt) {
        short4v p4;
        p4[0] = f2bs(o[dt][0] * inv); p4[1] = f2bs(o[dt][1] * inv);
        p4[2] = f2bs(o[dt][2] * inv); p4[3] = f2bs(o[dt][3] * inv);
        *reinterpret_cast<short4v*>(dst + dt * 16 + 4 * g) = p4;
    }
}

// ------------------------------------------------------------------
extern "C" void kernel_launch(void* const* d_in, const int* in_sizes, int n_in,
                              void* d_out, int out_size, void* d_ws, size_t ws_size,
                              hipStream_t stream)
{
    const float* query = (const float*)d_in[0];
    const float* key   = (const float*)d_in[1];
    const float* value = (const float*)d_in[2];
    // d_in[3] = mask: fixed causal tril — implemented directly
    const float* Wq = (const float*)d_in[4];
    const float* bq = (const float*)d_in[5];
    const float* Wk = (const float*)d_in[6];
    const float* bk = (const float*)d_in[7];
    const float* Wv = (const float*)d_in[8];
    const float* bv = (const float*)d_in[9];
    const float* Wo = (const float*)d_in[10];
    const float* bo = (const float*)d_in[11];
    float* out = (float*)d_out;

    char* ws = (char*)d_ws;
    const size_t MB = 1024 * 1024;
    unsigned short* xq  = (unsigned short*)(ws + 0 * MB);
    unsigned short* xk  = (unsigned short*)(ws + 8 * MB);
    unsigned short* xv  = (unsigned short*)(ws + 16 * MB);
    unsigned short* wqb = (unsigned short*)(ws + 24 * MB);
    unsigned short* wkb = (unsigned short*)(ws + 26 * MB);
    unsigned short* wvb = (unsigned short*)(ws + 28 * MB);
    unsigned short* wob = (unsigned short*)(ws + 30 * MB);
    __hip_bfloat16* qb  = (__hip_bfloat16*)(ws + 32 * MB);
    __hip_bfloat16* kb  = (__hip_bfloat16*)(ws + 40 * MB);
    __hip_bfloat16* vb  = (__hip_bfloat16*)(ws + 48 * MB);
    __hip_bfloat16* ctx = (__hip_bfloat16*)(ws + 56 * MB);

    ConvArgs ca;
    ca.src[0] = query; ca.dst[0] = xq;  ca.nblk[0] = 2048;
    ca.src[1] = key;   ca.dst[1] = xk;  ca.nblk[1] = 2048;
    ca.src[2] = value; ca.dst[2] = xv;  ca.nblk[2] = 2048;
    ca.src[3] = Wq;    ca.dst[3] = wqb; ca.nblk[3] = 512;
    ca.src[4] = Wk;    ca.dst[4] = wkb; ca.nblk[4] = 512;
    ca.src[5] = Wv;    ca.dst[5] = wvb; ca.nblk[5] = 512;
    ca.src[6] = Wo;    ca.dst[6] = wob; ca.nblk[6] = 512;
    convert_bf16_kernel<<<dim3(8192), dim3(256), 0, stream>>>(ca);

    TrioArgs ta;
    // Q scale folds 1/sqrt(64) AND log2(e) for the exp2-domain softmax.
    ta.X[0] = (const short*)xq; ta.W[0] = (const short*)wqb; ta.bias[0] = bq;
    ta.out[0] = qb; ta.scale[0] = 0.125f * 1.44269504f;
    ta.X[1] = (const short*)xk; ta.W[1] = (const short*)wkb; ta.bias[1] = bk;
    ta.out[1] = kb; ta.scale[1] = 1.0f;
    ta.X[2] = (const short*)xv; ta.W[2] = (const short*)wvb; ta.bias[2] = bv;
    ta.out[2] = vb; ta.scale[2] = 1.0f;
    gemm_qkv_kernel<<<dim3(768), dim3(256), 0, stream>>>(ta);

    attn_mfma_kernel<<<dim3(512), dim3(512), 0, stream>>>(qb, kb, vb, ctx);

    gemm_out_kernel<<<dim3(256), dim3(256), 0, stream>>>(
        (const short*)ctx, (const short*)wob, bo, out);
}